// Round 4
// baseline (181.169 us; speedup 1.0000x reference)
//
#include <hip/hip_runtime.h>

// Problem constants (fixed by the reference)
#define BATCH 128
#define C 64
#define L 4096
#define K 31

// Tiling: 1024 blocks (8 tiles x 128 batch), 256 threads = 4 waves.
// Each wave computes the FULL 512-output tile partial-sum over ITS 16
// channels (software-pipelined windows), then a 4-way LDS reduce, then all
// 4 waves broadcast-store 16 output channels each.
#define NT 256
#define NWAVE 4
#define CPW (C / NWAVE)           // 16 channels per wave
#define R 8                       // outputs per lane
#define TILE 512                  // 64 lanes * R
#define WIN 40                    // aligned window [l0-16, l0+24)

typedef float floatx4 __attribute__((ext_vector_type(4)));

// out[b,o,l] = S[b,l] for all o (kernel broadcast over o), where
//   S[b,l] = sum_i sum_k w[i,k] * x[b,i,l+15-k]   (x zero outside [0,L))
__global__ __launch_bounds__(NT, 4)
void revconv_kernel(const float* __restrict__ x,
                    const float* __restrict__ w,
                    float* __restrict__ out) {
    __shared__ __align__(16) float psum[NWAVE][TILE];
    __shared__ __align__(16) float fS[TILE];

    const int tid  = threadIdx.x;
    const int wave = tid >> 6;
    const int lane = tid & 63;
    const int tile = blockIdx.x;          // 0..7
    const int b    = blockIdx.y;          // 0..127
    const int lt   = lane * R;            // within-tile output start
    const int l0   = tile * TILE + lt;    // global output start

    const float* xb = x + (long)b * C * L;
    const int i0 = wave * CPW;

    float acc[R];
#pragma unroll
    for (int r = 0; r < R; ++r) acc[r] = 0.f;

    const bool interior = (l0 >= 16) && (l0 + 24 <= L);

    if (interior) {
        const float* xw = xb + (l0 - 16);   // 16B-aligned (l0 % 8 == 0)
        float winA[WIN], winB[WIN];
        // preload channel i0 into winA
        {
            const floatx4* p = reinterpret_cast<const floatx4*>(xw + (long)i0 * L);
#pragma unroll
            for (int j = 0; j < WIN / 4; ++j)
                reinterpret_cast<floatx4*>(winA)[j] = p[j];
        }
        for (int c = 0; c < CPW; c += 2) {
            // prefetch channel c+1 into winB
            {
                const floatx4* p = reinterpret_cast<const floatx4*>(xw + (long)(i0 + c + 1) * L);
#pragma unroll
                for (int j = 0; j < WIN / 4; ++j)
                    reinterpret_cast<floatx4*>(winB)[j] = p[j];
            }
            // compute channel c from winA
            {
                const float* wp = w + (i0 + c) * K;   // wave-uniform -> s_load
#pragma unroll
                for (int k = 0; k < K; ++k) {
                    const float wk = wp[k];
#pragma unroll
                    for (int r = 0; r < R; ++r)
                        acc[r] += wk * winA[r + 31 - k];
                }
            }
            // prefetch channel c+2 into winA
            if (c + 2 < CPW) {
                const floatx4* p = reinterpret_cast<const floatx4*>(xw + (long)(i0 + c + 2) * L);
#pragma unroll
                for (int j = 0; j < WIN / 4; ++j)
                    reinterpret_cast<floatx4*>(winA)[j] = p[j];
            }
            // compute channel c+1 from winB
            {
                const float* wp = w + (i0 + c + 1) * K;
#pragma unroll
                for (int k = 0; k < K; ++k) {
                    const float wk = wp[k];
#pragma unroll
                    for (int r = 0; r < R; ++r)
                        acc[r] += wk * winB[r + 31 - k];
                }
            }
        }
    } else {
        // Edge lanes (2 per wave in tiles 0 and 7): guarded scalar loads.
        for (int c = 0; c < CPW; ++c) {
            const float* xi = xb + (long)(i0 + c) * L;
            float win[WIN];
#pragma unroll
            for (int j = 0; j < WIN; ++j) {
                const int g = l0 - 16 + j;
                win[j] = (g >= 0 && g < L) ? xi[g] : 0.f;
            }
            const float* wp = w + (i0 + c) * K;
#pragma unroll
            for (int k = 0; k < K; ++k) {
                const float wk = wp[k];
#pragma unroll
                for (int r = 0; r < R; ++r)
                    acc[r] += wk * win[r + 31 - k];
            }
        }
    }

    // ---- 4-way cross-wave reduction in LDS ----
    floatx4 a0, a1;
    a0.x = acc[0]; a0.y = acc[1]; a0.z = acc[2]; a0.w = acc[3];
    a1.x = acc[4]; a1.y = acc[5]; a1.z = acc[6]; a1.w = acc[7];
    *reinterpret_cast<floatx4*>(&psum[wave][lt])     = a0;
    *reinterpret_cast<floatx4*>(&psum[wave][lt + 4]) = a1;
    __syncthreads();
    {
        const int e = tid * 2;
        fS[e]     = psum[0][e]     + psum[1][e]     + psum[2][e]     + psum[3][e];
        fS[e + 1] = psum[0][e + 1] + psum[1][e + 1] + psum[2][e + 1] + psum[3][e + 1];
    }
    __syncthreads();

    // ---- broadcast-store: wave handles channels [wave*16, wave*16+16) ----
    const floatx4 v0 = *reinterpret_cast<const floatx4*>(&fS[lane * 4]);
    const floatx4 v1 = *reinterpret_cast<const floatx4*>(&fS[lane * 4 + 256]);
    float* ob = out + ((long)b * C + i0) * L + tile * TILE;
#pragma unroll
    for (int o = 0; o < CPW; ++o) {
        float* op = ob + (long)o * L;
        __builtin_nontemporal_store(v0, reinterpret_cast<floatx4*>(op + lane * 4));
        __builtin_nontemporal_store(v1, reinterpret_cast<floatx4*>(op + lane * 4 + 256));
    }
}

extern "C" void kernel_launch(void* const* d_in, const int* in_sizes, int n_in,
                              void* d_out, int out_size, void* d_ws, size_t ws_size,
                              hipStream_t stream) {
    const float* x = (const float*)d_in[0];   // [B, C, L] fp32
    const float* w = (const float*)d_in[1];   // [C, C, K] fp32; o=0 slice used
    float* out = (float*)d_out;               // [B, C, L] fp32

    dim3 grid(L / TILE, BATCH);
    dim3 block(NT);
    revconv_kernel<<<grid, block, 0, stream>>>(x, w, out);
}